// Round 2
// baseline (1143.414 us; speedup 1.0000x reference)
//
#include <hip/hip_runtime.h>
#include <math.h>

// N=511 complete binary tree: nodes 0..254 internal (both children valid),
// 255..510 leaves (no valid children). B=128, M=256, IN=512, R=64.
#define NNODE 511

typedef short s16x8 __attribute__((ext_vector_type(8)));
typedef float f32x4 __attribute__((ext_vector_type(4)));

__device__ __forceinline__ unsigned short f2bf(float f) {
  unsigned int u = __builtin_bit_cast(unsigned int, f);
  u += 0x7fffu + ((u >> 16) & 1u);           // RNE
  return (unsigned short)(u >> 16);
}
__device__ __forceinline__ float sigf(float x) { return 1.0f / (1.0f + expf(-x)); }

// ---------------------------------------------------------------------------
// Stage a chunk of leaf x: wte (B,511,512) fp32 -> xchunk (rows,512) bf16,
// row r = vloc*128 + b, node = node0 + vloc.
__global__ void k_prep_xchunk(const float* __restrict__ w, unsigned short* __restrict__ xc,
                              int node0) {
  int o = (blockIdx.x * 256 + threadIdx.x) * 4;   // element index: r*512 + k
  int r = o >> 9;
  int k = o & 511;
  int vloc = r >> 7, b = r & 127;
  int node = node0 + vloc;
  const float4 v = *(const float4*)(w + ((size_t)b * NNODE + node) * 512 + k);
  unsigned int p0 = (unsigned int)f2bf(v.x) | ((unsigned int)f2bf(v.y) << 16);
  unsigned int p1 = (unsigned int)f2bf(v.z) | ((unsigned int)f2bf(v.w) << 16);
  *(uint2*)(xc + o) = make_uint2(p0, p1);
}

// Build transposed bf16 weight mats:
//  WLt  (768,512):  [Wix|Wux|Wox] columns, for leaf gates
//  WAt  (1280,320): cols 0:1024 = W_seq_ih (i,f,g,o), cols 1024:1280 = [Wfh;0]
//  WHHt (1024,256): W_seq_hh
//  WEXt (1024,768): k<256 -> [Wih|Wuh|Woh|0], k>=256 -> [Wix|Wux|Wox|Wfx]
__global__ void k_prep_w(const float* __restrict__ Wix, const float* __restrict__ Wux,
                         const float* __restrict__ Wox, const float* __restrict__ Wfx,
                         const float* __restrict__ Wih, const float* __restrict__ Wuh,
                         const float* __restrict__ Woh, const float* __restrict__ Wfh,
                         const float* __restrict__ Wsi, const float* __restrict__ Wsh,
                         unsigned short* __restrict__ WLt, unsigned short* __restrict__ WAt,
                         unsigned short* __restrict__ WHHt, unsigned short* __restrict__ WEXt) {
  int idx = blockIdx.x * 256 + threadIdx.x;
  if (idx < 393216) {                       // WLt: 768*512
    int n = idx >> 9, k = idx & 511;
    const float* W = (n < 256) ? Wix : (n < 512) ? Wux : Wox;
    WLt[idx] = f2bf(W[k * 256 + (n & 255)]);
  } else if (idx < 802816) {                // WAt: 1280*320
    int o = idx - 393216;
    int n = o / 320, k = o - n * 320;
    float v;
    if (n < 1024) v = Wsi[k * 1024 + n];
    else          v = (k < 256) ? Wfh[k * 256 + (n - 1024)] : 0.0f;
    WAt[o] = f2bf(v);
  } else if (idx < 1064960) {               // WHHt: 1024*256
    int o = idx - 802816;
    int n = o >> 8, k = o & 255;
    WHHt[o] = f2bf(Wsh[k * 1024 + n]);
  } else if (idx < 1851392) {               // WEXt: 1024*768
    int o = idx - 1064960;
    int n = o / 768, k = o - n * 768;
    float v;
    if (k < 256) {
      v = (n < 256) ? Wih[k * 256 + n]
        : (n < 512) ? Wuh[k * 256 + (n - 256)]
        : (n < 768) ? Woh[k * 256 + (n - 512)] : 0.0f;
    } else {
      int k2 = k - 256;
      v = (n < 256) ? Wix[k2 * 256 + n]
        : (n < 512) ? Wux[k2 * 256 + (n - 256)]
        : (n < 768) ? Wox[k2 * 256 + (n - 512)]
        :             Wfx[k2 * 256 + (n - 768)];
    }
    WEXt[o] = f2bf(v);
  }
}

// ---------------------------------------------------------------------------
// bf16 NT GEMM: C(rows,Ncols) fp32 {=, +=} A(rows,K) * Bt(Ncols,K)^T
// 128x128 tile, BK=64, 4 waves x 64x64 via 4x4 mfma_16x16x32_bf16.
// LDS rows padded to 72 elems; output stride ldc; accum adds to existing C.
__global__ __launch_bounds__(256) void k_gemm(
    const unsigned short* __restrict__ A, const unsigned short* __restrict__ Bt,
    float* __restrict__ C, int K, int ldc, int accum) {
  __shared__ alignas(16) unsigned short As[128 * 72];
  __shared__ alignas(16) unsigned short Bs[128 * 72];
  const int t = threadIdx.x;
  const int wave = t >> 6, lane = t & 63;
  const int wm = (wave & 1) * 64, wn = (wave >> 1) * 64;
  const int m16 = lane & 15, q = lane >> 4;
  const int rowBase = blockIdx.y * 128;
  const int colBase = blockIdx.x * 128;

  f32x4 acc[4][4] = {};

  for (int k0 = 0; k0 < K; k0 += 64) {
#pragma unroll
    for (int c = 0; c < 4; ++c) {
      int chunk = t + 256 * c;           // 1024 chunks of 8 bf16 per tile
      int row = chunk >> 3;
      int kc  = (chunk & 7) << 3;
      int4 va = *(const int4*)(A  + (size_t)(rowBase + row) * K + k0 + kc);
      int4 vb = *(const int4*)(Bt + (size_t)(colBase + row) * K + k0 + kc);
      *(int4*)(&As[row * 72 + kc]) = va;
      *(int4*)(&Bs[row * 72 + kc]) = vb;
    }
    __syncthreads();
#pragma unroll
    for (int kk = 0; kk < 64; kk += 32) {
      s16x8 af[4], bfr[4];
#pragma unroll
      for (int i = 0; i < 4; ++i)
        af[i] = *(const s16x8*)(&As[(wm + i * 16 + m16) * 72 + kk + q * 8]);
#pragma unroll
      for (int j = 0; j < 4; ++j)
        bfr[j] = *(const s16x8*)(&Bs[(wn + j * 16 + m16) * 72 + kk + q * 8]);
#pragma unroll
      for (int i = 0; i < 4; ++i)
#pragma unroll
        for (int j = 0; j < 4; ++j)
          acc[i][j] = __builtin_amdgcn_mfma_f32_16x16x32_bf16(af[i], bfr[j], acc[i][j], 0, 0, 0);
    }
    __syncthreads();
  }
  // C/D layout: col = lane&15, row = (lane>>4)*4 + reg  [verified m89/m91]
#pragma unroll
  for (int i = 0; i < 4; ++i) {
    int row0 = rowBase + wm + i * 16 + q * 4;
#pragma unroll
    for (int j = 0; j < 4; ++j) {
      int col = colBase + wn + j * 16 + m16;
      if (accum) {
#pragma unroll
        for (int r2 = 0; r2 < 4; ++r2)
          C[(size_t)(row0 + r2) * ldc + col] += acc[i][j][r2];
      } else {
#pragma unroll
        for (int r2 = 0; r2 < 4; ++r2)
          C[(size_t)(row0 + r2) * ldc + col] = acc[i][j][r2];
      }
    }
  }
}

// ---------------------------------------------------------------------------
// Leaf epilogue: i,u,o gates -> c (cbuf), h -> parent Ain; rel -> Ain.
// Lpre = Apre with ldc 1280, cols [i|u|o].
__global__ void k_leaf_final(const float* __restrict__ Lpre,
    const float* __restrict__ bix, const float* __restrict__ bih,
    const float* __restrict__ bux, const float* __restrict__ buh,
    const float* __restrict__ box, const float* __restrict__ boh,
    float* __restrict__ cbuf, unsigned short* __restrict__ Ain,
    const float* __restrict__ rel, int v0) {
  int idx = blockIdx.x * 256 + threadIdx.x;
  int r = idx >> 8, m = idx & 255;
  int vg = v0 + (r >> 7), b = r & 127;
  int node = 255 + vg;
  const float* g = Lpre + (size_t)r * 1280;
  float i = sigf(g[m] + bix[m] + bih[m]);
  float u = tanhf(g[256 + m] + bux[m] + buh[m]);
  float o = sigf(g[512 + m] + box[m] + boh[m]);
  float c = i * u;
  float h = o * tanhf(c);
  cbuf[((size_t)node * 128 + b) * 256 + m] = c;
  int rowA = (vg & 1) * 16384 + (vg >> 1) * 128 + b;   // parent level 7: nB=16384
  Ain[(size_t)rowA * 320 + m] = f2bf(h);
  if (m < 64) Ain[(size_t)rowA * 320 + 256 + m] = f2bf(rel[((size_t)b * NNODE + node) * 64 + m]);
}

// Seq-LSTM cell 1 (h=0,c=0): g = ApreL[r, 0:1024] + b_seq
__global__ void k_cell1(const float* __restrict__ ApreL,
    const float* __restrict__ bsi, const float* __restrict__ bsh,
    unsigned short* __restrict__ h1, float* __restrict__ c1) {
  int idx = blockIdx.x * 256 + threadIdx.x;
  int r = idx >> 8, m = idx & 255;
  const float* g = ApreL + (size_t)r * 1280;
  float i  = sigf(g[m] + bsi[m] + bsh[m]);
  float gg = tanhf(g[512 + m] + bsi[512 + m] + bsh[512 + m]);
  float o  = sigf(g[768 + m] + bsi[768 + m] + bsh[768 + m]);
  float c = i * gg;
  float h = o * tanhf(c);
  c1[idx] = c;
  h1[idx] = f2bf(h);
}

// Seq-LSTM cell 2: g = ApreR[r,0:1024] (already += h1@Whh) + b_seq.
// h_tilde -> EXin[:,0:256]; x (fp32->bf16 on the fly) -> EXin[:,256:768].
__global__ void k_cell2(const float* __restrict__ ApreR, const float* __restrict__ c1,
    const float* __restrict__ wte,
    const float* __restrict__ bsi, const float* __restrict__ bsh,
    unsigned short* __restrict__ EXin, int node0) {
  int idx = blockIdx.x * 256 + threadIdx.x;
  int r = idx / 768, t = idx - r * 768;
  if (t >= 256) {
    int node = node0 + (r >> 7), b = r & 127;
    EXin[idx] = f2bf(wte[((size_t)b * NNODE + node) * 512 + (t - 256)]);
  } else {
    int m = t;
    const float* g = ApreR + (size_t)r * 1280;
    float i  = sigf(g[m] + bsi[m] + bsh[m]);
    float f  = sigf(g[256 + m] + bsi[256 + m] + bsh[256 + m]);
    float gg = tanhf(g[512 + m] + bsi[512 + m] + bsh[512 + m]);
    float o  = sigf(g[768 + m] + bsi[768 + m] + bsh[768 + m]);
    float c2 = f * c1[(size_t)r * 256 + m] + i * gg;
    EXin[(size_t)r * 768 + m] = f2bf(o * tanhf(c2));
  }
}

// Node-gate epilogue. EXpre = Apre-left cols 0:1024 (ldc 1280), f-preacts in
// col 1024+m of Apre left/right blocks. lvl>0: write cbuf + parent Ain.
// lvl==0: write d_out fp32.
__global__ void k_final(const float* __restrict__ Apre,
    const float* __restrict__ bix, const float* __restrict__ bih,
    const float* __restrict__ bux, const float* __restrict__ buh,
    const float* __restrict__ box, const float* __restrict__ boh,
    const float* __restrict__ bfx, const float* __restrict__ bfh,
    float* __restrict__ cbuf, unsigned short* __restrict__ Ain,
    const float* __restrict__ rel, float* __restrict__ out,
    int crows, int base, int v0, int n, int lvl) {
  int idx = blockIdx.x * 256 + threadIdx.x;
  int r = idx >> 8, m = idx & 255;
  int vloc = r >> 7, b = r & 127;
  int vg = v0 + vloc;
  int node = base + vg;
  int ch0 = 2 * node + 1;
  const float* g = Apre + (size_t)r * 1280;
  float pi = g[m]       + bix[m] + bih[m];
  float pu = g[256 + m] + bux[m] + buh[m];
  float po = g[512 + m] + box[m] + boh[m];
  float pf = g[768 + m] + bfx[m] + bfh[m];
  float f0 = sigf(pf + Apre[(size_t)r * 1280 + 1024 + m]);
  float f1 = sigf(pf + Apre[(size_t)(crows + r) * 1280 + 1024 + m]);
  float i = sigf(pi), u = tanhf(pu), o = sigf(po);
  float c = i * u + f0 * cbuf[((size_t)ch0 * 128 + b) * 256 + m]
                  + f1 * cbuf[((size_t)(ch0 + 1) * 128 + b) * 256 + m];
  float h = o * tanhf(c);
  if (lvl == 0) {
    out[b * 256 + m] = h;
  } else {
    cbuf[((size_t)node * 128 + b) * 256 + m] = c;
    int rowA = (vg & 1) * (n >> 1) * 128 + (vg >> 1) * 128 + b;
    Ain[(size_t)rowA * 320 + m] = f2bf(h);
    if (m < 64) Ain[(size_t)rowA * 320 + 256 + m] = f2bf(rel[((size_t)b * NNODE + node) * 64 + m]);
  }
}

// ---------------------------------------------------------------------------
extern "C" void kernel_launch(void* const* d_in, const int* in_sizes, int n_in,
                              void* d_out, int out_size, void* d_ws, size_t ws_size,
                              hipStream_t stream) {
  const float* wte = (const float*)d_in[0];
  const float* rel = (const float*)d_in[1];
  const float* Wix = (const float*)d_in[3];
  const float* bix = (const float*)d_in[4];
  const float* Wfx = (const float*)d_in[5];
  const float* bfx = (const float*)d_in[6];
  const float* Wux = (const float*)d_in[7];
  const float* bux = (const float*)d_in[8];
  const float* Wox = (const float*)d_in[9];
  const float* box = (const float*)d_in[10];
  const float* Wih = (const float*)d_in[11];
  const float* bih = (const float*)d_in[12];
  const float* Wfh = (const float*)d_in[13];
  const float* bfh = (const float*)d_in[14];
  const float* Wuh = (const float*)d_in[15];
  const float* buh = (const float*)d_in[16];
  const float* Woh = (const float*)d_in[17];
  const float* boh = (const float*)d_in[18];
  const float* Wsi = (const float*)d_in[19];
  const float* Wsh = (const float*)d_in[20];
  const float* bsi = (const float*)d_in[21];
  const float* bsh = (const float*)d_in[22];
  float* out = (float*)d_out;
  (void)in_sizes; (void)n_in; (void)out_size;

  // Chunk sizes adapted to available workspace (constant across calls).
  int LEAF_CHUNK, INT_MAXN;
  if (ws_size >= (size_t)360 * 1024 * 1024)      { LEAF_CHUNK = 256; INT_MAXN = 128; }
  else if (ws_size >= (size_t)160 * 1024 * 1024) { LEAF_CHUNK = 64;  INT_MAXN = 32;  }
  else                                           { LEAF_CHUNK = 16;  INT_MAXN = 8;   }
  const int apreRows = 2 * INT_MAXN * 128;       // == LEAF_CHUNK*128 in all presets

  char* ws = (char*)d_ws;
  size_t off = 0;
  auto alloc = [&](size_t bytes) {
    size_t o = off; off += (bytes + 255) & ~(size_t)255; return o;
  };
  float*          cbuf = (float*)         (ws + alloc((size_t)NNODE * 128 * 256 * 4));
  unsigned short* Ain  = (unsigned short*)(ws + alloc((size_t)32768 * 320 * 2));
  unsigned short* WLt  = (unsigned short*)(ws + alloc((size_t)768 * 512 * 2));
  unsigned short* WAt  = (unsigned short*)(ws + alloc((size_t)1280 * 320 * 2));
  unsigned short* WHHt = (unsigned short*)(ws + alloc((size_t)1024 * 256 * 2));
  unsigned short* WEXt = (unsigned short*)(ws + alloc((size_t)1024 * 768 * 2));
  unsigned short* xc   = (unsigned short*)(ws + alloc((size_t)apreRows * 512 * 2));
  float*          Apre = (float*)         (ws + alloc((size_t)apreRows * 1280 * 4));
  unsigned short* h1   = (unsigned short*)(ws + alloc((size_t)(apreRows / 2) * 256 * 2));
  float*          c1   = (float*)         (ws + alloc((size_t)(apreRows / 2) * 256 * 4));
  unsigned short* EXin = (unsigned short*)(ws + alloc((size_t)(apreRows / 2) * 768 * 2));

  k_prep_w<<<7232, 256, 0, stream>>>(Wix, Wux, Wox, Wfx, Wih, Wuh, Woh, Wfh,
                                     Wsi, Wsh, WLt, WAt, WHHt, WEXt);

  // --- leaves: nodes 255..510, chunks of LEAF_CHUNK nodes ---
  for (int v0 = 0; v0 < 256; v0 += LEAF_CHUNK) {
    int rows = LEAF_CHUNK * 128;
    k_prep_xchunk<<<rows / 2, 256, 0, stream>>>(wte, xc, 255 + v0);
    k_gemm<<<dim3(6, rows / 128), 256, 0, stream>>>(xc, WLt, Apre, 512, 1280, 0);
    k_leaf_final<<<rows, 256, 0, stream>>>(Apre, bix, bih, bux, buh, box, boh,
                                           cbuf, Ain, rel, v0);
  }

  // --- internal levels 7..0 ---
  for (int lvl = 7; lvl >= 0; --lvl) {
    int n = 1 << lvl;
    int base = n - 1;
    int cn = (n < INT_MAXN) ? n : INT_MAXN;
    for (int v0 = 0; v0 < n; v0 += cn) {
      int crows = cn * 128;
      const unsigned short* AinL = Ain + (size_t)(v0 * 128) * 320;
      const unsigned short* AinR = Ain + (size_t)((n + v0) * 128) * 320;
      float* ApreR = Apre + (size_t)crows * 1280;
      // children pre-acts: [h|r] @ WAt -> cell gates (0:1024) + f gate (1024:1280)
      k_gemm<<<dim3(10, cn), 256, 0, stream>>>(AinL, WAt, Apre,  320, 1280, 0);
      k_gemm<<<dim3(10, cn), 256, 0, stream>>>(AinR, WAt, ApreR, 320, 1280, 0);
      k_cell1<<<crows, 256, 0, stream>>>(Apre, bsi, bsh, h1, c1);
      // h1 @ Whh accumulated onto right-child cell pre-acts
      k_gemm<<<dim3(8, cn), 256, 0, stream>>>(h1, WHHt, ApreR, 256, 1280, 1);
      k_cell2<<<crows * 3, 256, 0, stream>>>(ApreR, c1, wte, bsi, bsh, EXin, base + v0);
      // [h_tilde|x] @ WEXt -> node gates, aliased into Apre-left cols 0:1024
      k_gemm<<<dim3(8, cn), 256, 0, stream>>>(EXin, WEXt, Apre, 768, 1280, 0);
      k_final<<<crows, 256, 0, stream>>>(Apre, bix, bih, bux, buh, box, boh, bfx, bfh,
                                         cbuf, Ain, rel, out, crows, base, v0, n, lvl);
    }
  }
}

// Round 3
// 1124.412 us; speedup vs baseline: 1.0169x; 1.0169x over previous
//
#include <hip/hip_runtime.h>
#include <math.h>

// N=511 complete binary tree: nodes 0..254 internal (both children valid),
// 255..510 leaves. B=128, M=256, IN=512, R=64.
// Gate-interleaved bf16 weight layouts let every LSTM-cell epilogue fuse into
// its producing GEMM: each wave tile (64 rows x gates*16 cols) holds ALL gates
// for 16 m-columns in one lane's accumulators. 3 launches per tree level.
#define NNODE 511

typedef short s16x8 __attribute__((ext_vector_type(8)));
typedef float f32x4 __attribute__((ext_vector_type(4)));

__device__ __forceinline__ unsigned short f2bf(float f) {
  unsigned int u = __builtin_bit_cast(unsigned int, f);
  u += 0x7fffu + ((u >> 16) & 1u);           // RNE
  return (unsigned short)(u >> 16);
}
__device__ __forceinline__ float sigf(float x) { return 1.0f / (1.0f + expf(-x)); }

// pack 8 consecutive fp32 -> 8 bf16 (as uint4) for LDS staging
__device__ __forceinline__ uint4 pack8(const float* __restrict__ p) {
  float4 a = *(const float4*)p;
  float4 b = *(const float4*)(p + 4);
  uint4 r;
  r.x = (unsigned int)f2bf(a.x) | ((unsigned int)f2bf(a.y) << 16);
  r.y = (unsigned int)f2bf(a.z) | ((unsigned int)f2bf(a.w) << 16);
  r.z = (unsigned int)f2bf(b.x) | ((unsigned int)f2bf(b.y) << 16);
  r.w = (unsigned int)f2bf(b.z) | ((unsigned int)f2bf(b.w) << 16);
  return r;
}

// ---------------------------------------------------------------------------
// Gate-interleaved transposed weights (c = column index, k = reduction index):
//  WL2t (768,512):  c = 48G+16g+mi, g in {i,u,o};       src W{ix,ux,ox}[k][16G+mi]
//  WA2t (1280,320): c = 80G+16g+mi, g in {i,f,g,o,fh};  g<4: Wsi[k][g*256+m], g=4: k<256?Wfh[k][m]:0
//  WH2t (1024,256): c = 64G+16g+mi, g in {i,f,g,o};     Wsh[k][g*256+m]
//  WEX2t(1024,768): c = 64G+16g+mi, g in {i,u,o,f};     k<256: {Wih,Wuh,Woh,0}[k][m]; else {Wix,Wux,Wox,Wfx}[k-256][m]
__global__ void k_prep_w(const float* __restrict__ Wix, const float* __restrict__ Wux,
                         const float* __restrict__ Wox, const float* __restrict__ Wfx,
                         const float* __restrict__ Wih, const float* __restrict__ Wuh,
                         const float* __restrict__ Woh, const float* __restrict__ Wfh,
                         const float* __restrict__ Wsi, const float* __restrict__ Wsh,
                         unsigned short* __restrict__ WL2t, unsigned short* __restrict__ WA2t,
                         unsigned short* __restrict__ WH2t, unsigned short* __restrict__ WEX2t) {
  int idx = blockIdx.x * 256 + threadIdx.x;
  if (idx < 393216) {                       // WL2t 768*512
    int c = idx >> 9, k = idx & 511;
    int G = c / 48, rem = c - G * 48, g = rem >> 4, mi = rem & 15, m = G * 16 + mi;
    const float* W = (g == 0) ? Wix : (g == 1) ? Wux : Wox;
    WL2t[idx] = f2bf(W[k * 256 + m]);
  } else if (idx < 802816) {                // WA2t 1280*320
    int o = idx - 393216;
    int c = o / 320, k = o - c * 320;
    int G = c / 80, rem = c - G * 80, g = rem >> 4, mi = rem & 15, m = G * 16 + mi;
    float v;
    if (g < 4) v = Wsi[k * 1024 + g * 256 + m];
    else       v = (k < 256) ? Wfh[k * 256 + m] : 0.0f;
    WA2t[o] = f2bf(v);
  } else if (idx < 1064960) {               // WH2t 1024*256
    int o = idx - 802816;
    int c = o >> 8, k = o & 255;
    int G = c >> 6, rem = c & 63, g = rem >> 4, mi = rem & 15, m = G * 16 + mi;
    WH2t[o] = f2bf(Wsh[k * 1024 + g * 256 + m]);
  } else if (idx < 1851392) {               // WEX2t 1024*768
    int o = idx - 1064960;
    int c = o / 768, k = o - c * 768;
    int G = c >> 6, rem = c & 63, g = rem >> 4, mi = rem & 15, m = G * 16 + mi;
    float v;
    if (k < 256) {
      v = (g == 0) ? Wih[k * 256 + m] : (g == 1) ? Wuh[k * 256 + m]
        : (g == 2) ? Woh[k * 256 + m] : 0.0f;
    } else {
      int k2 = k - 256;
      v = (g == 0) ? Wix[k2 * 256 + m] : (g == 1) ? Wux[k2 * 256 + m]
        : (g == 2) ? Wox[k2 * 256 + m] : Wfx[k2 * 256 + m];
    }
    WEX2t[o] = f2bf(v);
  }
}

// Shared MFMA inner step (indices identical to the verified round-2 kernel).
#define MFMA_BODY(NG, CW)                                                     \
  _Pragma("unroll")                                                           \
  for (int kk = 0; kk < 64; kk += 32) {                                       \
    s16x8 af[4], bfr[NG];                                                     \
    _Pragma("unroll")                                                         \
    for (int i = 0; i < 4; ++i)                                               \
      af[i] = *(const s16x8*)(&As[(wm + i * 16 + m16) * 72 + kk + q * 8]);    \
    _Pragma("unroll")                                                         \
    for (int j = 0; j < NG; ++j)                                              \
      bfr[j] = *(const s16x8*)(&Bs[(wc * CW + j * 16 + m16) * 72 + kk + q * 8]); \
    _Pragma("unroll")                                                         \
    for (int i = 0; i < 4; ++i)                                               \
      _Pragma("unroll")                                                       \
      for (int j = 0; j < NG; ++j)                                            \
        acc[i][j] = __builtin_amdgcn_mfma_f32_16x16x32_bf16(af[i], bfr[j], acc[i][j], 0, 0, 0); \
  }

// ---------------------------------------------------------------------------
// GEMM1 + cell1 epilogue. A = [AinL ; AinR] (2*crows x 320 bf16), B = WA2t.
// L rows -> h1 (bf16), c1, FHL.  R rows -> PR (float4 i,f,g,o preacts), FHR.
__global__ __launch_bounds__(256) void k_gemm1(
    const unsigned short* __restrict__ AinL, const unsigned short* __restrict__ AinR,
    const unsigned short* __restrict__ Bt,
    unsigned short* __restrict__ h1, float* __restrict__ c1,
    float* __restrict__ FHL, float* __restrict__ FHR, float* __restrict__ PR,
    const float* __restrict__ bsi, const float* __restrict__ bsh, int crows) {
  __shared__ alignas(16) unsigned short As[128 * 72];
  __shared__ alignas(16) unsigned short Bs[160 * 72];
  const int t = threadIdx.x;
  const int wave = t >> 6, lane = t & 63;
  const int wm = (wave & 1) * 64, wc = wave >> 1;
  const int m16 = lane & 15, q = lane >> 4;
  const int rowBase = blockIdx.y * 128;
  const int colBase = blockIdx.x * 160;
  const bool isL = rowBase < crows;
  const unsigned short* Arow = isL ? (AinL + (size_t)rowBase * 320)
                                   : (AinR + (size_t)(rowBase - crows) * 320);
  f32x4 acc[4][5] = {};

  for (int k0 = 0; k0 < 320; k0 += 64) {
#pragma unroll
    for (int c = 0; c < 4; ++c) {          // A: 1024 chunks of 8
      int chunk = t + 256 * c;
      int row = chunk >> 3, kc = (chunk & 7) << 3;
      *(int4*)(&As[row * 72 + kc]) = *(const int4*)(Arow + (size_t)row * 320 + k0 + kc);
    }
#pragma unroll
    for (int c = 0; c < 5; ++c) {          // B: 1280 chunks of 8
      int chunk = t + 256 * c;
      int row = chunk >> 3, kc = (chunk & 7) << 3;
      *(int4*)(&Bs[row * 72 + kc]) = *(const int4*)(Bt + (size_t)(colBase + row) * 320 + k0 + kc);
    }
    __syncthreads();
    MFMA_BODY(5, 80)
    __syncthreads();
  }

  const int m = (blockIdx.x * 2 + wc) * 16 + m16;
  if (isL) {
    float bi = bsi[m] + bsh[m];
    float bg = bsi[512 + m] + bsh[512 + m];
    float bo = bsi[768 + m] + bsh[768 + m];
#pragma unroll
    for (int i = 0; i < 4; ++i)
#pragma unroll
      for (int r2 = 0; r2 < 4; ++r2) {
        int r = rowBase + wm + i * 16 + q * 4 + r2;
        float ii = sigf(acc[i][0][r2] + bi);
        float gg = tanhf(acc[i][2][r2] + bg);
        float oo = sigf(acc[i][3][r2] + bo);
        float cv = ii * gg;
        size_t o = (size_t)r * 256 + m;
        h1[o] = f2bf(oo * tanhf(cv));
        c1[o] = cv;
        FHL[o] = acc[i][4][r2];
      }
  } else {
#pragma unroll
    for (int i = 0; i < 4; ++i)
#pragma unroll
      for (int r2 = 0; r2 < 4; ++r2) {
        int rr = rowBase - crows + wm + i * 16 + q * 4 + r2;
        size_t o = (size_t)rr * 256 + m;
        float4 pv = {acc[i][0][r2], acc[i][1][r2], acc[i][2][r2], acc[i][3][r2]};
        *(float4*)(PR + o * 4) = pv;
        FHR[o] = acc[i][4][r2];
      }
  }
}

// ---------------------------------------------------------------------------
// GEMM2 + cell2 epilogue. A = h1 (crows x 256), B = WH2t.
// g = acc + PR + b_seq; h_tilde -> HT (bf16).
__global__ __launch_bounds__(256) void k_gemm2(
    const unsigned short* __restrict__ A, const unsigned short* __restrict__ Bt,
    const float* __restrict__ PR, const float* __restrict__ c1,
    unsigned short* __restrict__ HT,
    const float* __restrict__ bsi, const float* __restrict__ bsh) {
  __shared__ alignas(16) unsigned short As[128 * 72];
  __shared__ alignas(16) unsigned short Bs[128 * 72];
  const int t = threadIdx.x;
  const int wave = t >> 6, lane = t & 63;
  const int wm = (wave & 1) * 64, wc = wave >> 1;
  const int m16 = lane & 15, q = lane >> 4;
  const int rowBase = blockIdx.y * 128;
  const int colBase = blockIdx.x * 128;
  f32x4 acc[4][4] = {};

  for (int k0 = 0; k0 < 256; k0 += 64) {
#pragma unroll
    for (int c = 0; c < 4; ++c) {
      int chunk = t + 256 * c;
      int row = chunk >> 3, kc = (chunk & 7) << 3;
      *(int4*)(&As[row * 72 + kc]) = *(const int4*)(A + (size_t)(rowBase + row) * 256 + k0 + kc);
      *(int4*)(&Bs[row * 72 + kc]) = *(const int4*)(Bt + (size_t)(colBase + row) * 256 + k0 + kc);
    }
    __syncthreads();
    MFMA_BODY(4, 64)
    __syncthreads();
  }

  const int m = (blockIdx.x * 2 + wc) * 16 + m16;
  float b0 = bsi[m] + bsh[m];
  float b1 = bsi[256 + m] + bsh[256 + m];
  float b2 = bsi[512 + m] + bsh[512 + m];
  float b3 = bsi[768 + m] + bsh[768 + m];
#pragma unroll
  for (int i = 0; i < 4; ++i)
#pragma unroll
    for (int r2 = 0; r2 < 4; ++r2) {
      int r = rowBase + wm + i * 16 + q * 4 + r2;
      size_t o = (size_t)r * 256 + m;
      float4 pv = *(const float4*)(PR + o * 4);
      float ii = sigf(acc[i][0][r2] + pv.x + b0);
      float ff = sigf(acc[i][1][r2] + pv.y + b1);
      float gg = tanhf(acc[i][2][r2] + pv.z + b2);
      float oo = sigf(acc[i][3][r2] + pv.w + b3);
      float c2 = ff * c1[o] + ii * gg;
      HT[o] = f2bf(oo * tanhf(c2));
    }
}

// ---------------------------------------------------------------------------
// GEMM3 + node-gate epilogue. A = [HT | x(on-the-fly from wte)] (crows x 768),
// B = WEX2t (gates i,u,o,f). Uses FHL/FHR + children cbuf.
// lvl>0: write cbuf + parent Ain (h bf16, rel). lvl==0: write d_out fp32.
__global__ __launch_bounds__(256) void k_gemm3(
    const unsigned short* __restrict__ HT, const float* __restrict__ wte,
    const unsigned short* __restrict__ Bt,
    const float* __restrict__ FHL, const float* __restrict__ FHR,
    float* __restrict__ cbuf, unsigned short* __restrict__ Ain,
    const float* __restrict__ rel, float* __restrict__ out,
    const float* __restrict__ bix, const float* __restrict__ bih,
    const float* __restrict__ bux, const float* __restrict__ buh,
    const float* __restrict__ box, const float* __restrict__ boh,
    const float* __restrict__ bfx, const float* __restrict__ bfh,
    int base, int v0, int n, int lvl) {
  __shared__ alignas(16) unsigned short As[128 * 72];
  __shared__ alignas(16) unsigned short Bs[128 * 72];
  const int t = threadIdx.x;
  const int wave = t >> 6, lane = t & 63;
  const int wm = (wave & 1) * 64, wc = wave >> 1;
  const int m16 = lane & 15, q = lane >> 4;
  const int rowBase = blockIdx.y * 128;
  const int colBase = blockIdx.x * 128;
  f32x4 acc[4][4] = {};

  for (int k0 = 0; k0 < 768; k0 += 64) {
#pragma unroll
    for (int c = 0; c < 4; ++c) {
      int chunk = t + 256 * c;
      int row = chunk >> 3, kc = (chunk & 7) << 3;
      int gr = rowBase + row;
      if (k0 < 256) {
        *(int4*)(&As[row * 72 + kc]) = *(const int4*)(HT + (size_t)gr * 256 + k0 + kc);
      } else {
        int node = base + v0 + (gr >> 7), b = gr & 127;
        *(uint4*)(&As[row * 72 + kc]) =
            pack8(wte + ((size_t)b * NNODE + node) * 512 + (k0 - 256) + kc);
      }
      *(int4*)(&Bs[row * 72 + kc]) = *(const int4*)(Bt + (size_t)(colBase + row) * 768 + k0 + kc);
    }
    __syncthreads();
    MFMA_BODY(4, 64)
    __syncthreads();
  }

  const int m = (blockIdx.x * 2 + wc) * 16 + m16;
  float bi = bix[m] + bih[m];
  float bu = bux[m] + buh[m];
  float bo = box[m] + boh[m];
  float bf = bfx[m] + bfh[m];
#pragma unroll
  for (int i = 0; i < 4; ++i)
#pragma unroll
    for (int r2 = 0; r2 < 4; ++r2) {
      int r = rowBase + wm + i * 16 + q * 4 + r2;
      int vloc = r >> 7, b = r & 127;
      int vg = v0 + vloc;
      int node = base + vg;
      int ch0 = 2 * node + 1;
      size_t o = (size_t)r * 256 + m;
      float pf = acc[i][3][r2] + bf;
      float f0 = sigf(pf + FHL[o]);
      float f1 = sigf(pf + FHR[o]);
      float ii = sigf(acc[i][0][r2] + bi);
      float uu = tanhf(acc[i][1][r2] + bu);
      float oo = sigf(acc[i][2][r2] + bo);
      float cc = ii * uu + f0 * cbuf[((size_t)ch0 * 128 + b) * 256 + m]
                         + f1 * cbuf[((size_t)(ch0 + 1) * 128 + b) * 256 + m];
      float hh = oo * tanhf(cc);
      if (lvl == 0) {
        out[b * 256 + m] = hh;
      } else {
        cbuf[((size_t)node * 128 + b) * 256 + m] = cc;
        int rowA = (vg & 1) * (n >> 1) * 128 + (vg >> 1) * 128 + b;
        Ain[(size_t)rowA * 320 + m] = f2bf(hh);
        if (m < 64)
          Ain[(size_t)rowA * 320 + 256 + m] = f2bf(rel[((size_t)b * NNODE + node) * 64 + m]);
      }
    }
}

// ---------------------------------------------------------------------------
// Leaf GEMM + epilogue. A = x (on-the-fly from wte, 32768 x 512), B = WL2t
// (gates i,u,o). c = i*u; writes cbuf + level-7 Ain.
__global__ __launch_bounds__(256) void k_leaf(
    const float* __restrict__ wte, const unsigned short* __restrict__ Bt,
    float* __restrict__ cbuf, unsigned short* __restrict__ Ain,
    const float* __restrict__ rel,
    const float* __restrict__ bix, const float* __restrict__ bih,
    const float* __restrict__ bux, const float* __restrict__ buh,
    const float* __restrict__ box, const float* __restrict__ boh) {
  __shared__ alignas(16) unsigned short As[128 * 72];
  __shared__ alignas(16) unsigned short Bs[96 * 72];
  const int t = threadIdx.x;
  const int wave = t >> 6, lane = t & 63;
  const int wm = (wave & 1) * 64, wc = wave >> 1;
  const int m16 = lane & 15, q = lane >> 4;
  const int rowBase = blockIdx.y * 128;
  const int colBase = blockIdx.x * 96;
  f32x4 acc[4][3] = {};

  for (int k0 = 0; k0 < 512; k0 += 64) {
#pragma unroll
    for (int c = 0; c < 4; ++c) {          // A from wte fp32 -> bf16
      int chunk = t + 256 * c;
      int row = chunk >> 3, kc = (chunk & 7) << 3;
      int gr = rowBase + row;
      int node = 255 + (gr >> 7), b = gr & 127;
      *(uint4*)(&As[row * 72 + kc]) =
          pack8(wte + ((size_t)b * NNODE + node) * 512 + k0 + kc);
    }
#pragma unroll
    for (int c = 0; c < 3; ++c) {          // B: 768 chunks
      int chunk = t + 256 * c;
      int row = chunk >> 3, kc = (chunk & 7) << 3;
      *(int4*)(&Bs[row * 72 + kc]) = *(const int4*)(Bt + (size_t)(colBase + row) * 512 + k0 + kc);
    }
    __syncthreads();
    MFMA_BODY(3, 48)
    __syncthreads();
  }

  const int m = (blockIdx.x * 2 + wc) * 16 + m16;
  float bi = bix[m] + bih[m];
  float bu = bux[m] + buh[m];
  float bo = box[m] + boh[m];
#pragma unroll
  for (int i = 0; i < 4; ++i)
#pragma unroll
    for (int r2 = 0; r2 < 4; ++r2) {
      int r = rowBase + wm + i * 16 + q * 4 + r2;
      int vg = r >> 7, b = r & 127;
      int node = 255 + vg;
      float ii = sigf(acc[i][0][r2] + bi);
      float uu = tanhf(acc[i][1][r2] + bu);
      float oo = sigf(acc[i][2][r2] + bo);
      float cc = ii * uu;
      float hh = oo * tanhf(cc);
      cbuf[((size_t)node * 128 + b) * 256 + m] = cc;
      int rowA = (vg & 1) * 16384 + (vg >> 1) * 128 + b;
      Ain[(size_t)rowA * 320 + m] = f2bf(hh);
      if (m < 64)
        Ain[(size_t)rowA * 320 + 256 + m] = f2bf(rel[((size_t)b * NNODE + node) * 64 + m]);
    }
}

// ---------------------------------------------------------------------------
extern "C" void kernel_launch(void* const* d_in, const int* in_sizes, int n_in,
                              void* d_out, int out_size, void* d_ws, size_t ws_size,
                              hipStream_t stream) {
  const float* wte = (const float*)d_in[0];
  const float* rel = (const float*)d_in[1];
  const float* Wix = (const float*)d_in[3];
  const float* bix = (const float*)d_in[4];
  const float* Wfx = (const float*)d_in[5];
  const float* bfx = (const float*)d_in[6];
  const float* Wux = (const float*)d_in[7];
  const float* bux = (const float*)d_in[8];
  const float* Wox = (const float*)d_in[9];
  const float* box = (const float*)d_in[10];
  const float* Wih = (const float*)d_in[11];
  const float* bih = (const float*)d_in[12];
  const float* Wfh = (const float*)d_in[13];
  const float* bfh = (const float*)d_in[14];
  const float* Wuh = (const float*)d_in[15];
  const float* buh = (const float*)d_in[16];
  const float* Woh = (const float*)d_in[17];
  const float* boh = (const float*)d_in[18];
  const float* Wsi = (const float*)d_in[19];
  const float* Wsh = (const float*)d_in[20];
  const float* bsi = (const float*)d_in[21];
  const float* bsh = (const float*)d_in[22];
  float* out = (float*)d_out;
  (void)in_sizes; (void)n_in; (void)out_size;

  int INT_MAXN;
  if (ws_size >= (size_t)240 * 1024 * 1024)      INT_MAXN = 128;
  else if (ws_size >= (size_t)130 * 1024 * 1024) INT_MAXN = 32;
  else                                           INT_MAXN = 8;
  const int crowsMax = INT_MAXN * 128;

  char* ws = (char*)d_ws;
  size_t off = 0;
  auto alloc = [&](size_t bytes) {
    size_t o = off; off += (bytes + 255) & ~(size_t)255; return o;
  };
  float*          cbuf = (float*)         (ws + alloc((size_t)NNODE * 128 * 256 * 4));
  unsigned short* Ain  = (unsigned short*)(ws + alloc((size_t)32768 * 320 * 2));
  unsigned short* WL2t = (unsigned short*)(ws + alloc((size_t)768 * 512 * 2));
  unsigned short* WA2t = (unsigned short*)(ws + alloc((size_t)1280 * 320 * 2));
  unsigned short* WH2t = (unsigned short*)(ws + alloc((size_t)1024 * 256 * 2));
  unsigned short* WEX2t= (unsigned short*)(ws + alloc((size_t)1024 * 768 * 2));
  unsigned short* h1   = (unsigned short*)(ws + alloc((size_t)crowsMax * 256 * 2));
  float*          c1   = (float*)         (ws + alloc((size_t)crowsMax * 256 * 4));
  float*          FHL  = (float*)         (ws + alloc((size_t)crowsMax * 256 * 4));
  float*          FHR  = (float*)         (ws + alloc((size_t)crowsMax * 256 * 4));
  float*          PR   = (float*)         (ws + alloc((size_t)crowsMax * 1024 * 4));
  unsigned short* HT   = (unsigned short*)(ws + alloc((size_t)crowsMax * 256 * 2));

  k_prep_w<<<7232, 256, 0, stream>>>(Wix, Wux, Wox, Wfx, Wih, Wuh, Woh, Wfh,
                                     Wsi, Wsh, WL2t, WA2t, WH2t, WEX2t);

  // Leaves: one fused GEMM (x converted on the fly; no intermediates).
  k_leaf<<<dim3(8, 256), 256, 0, stream>>>(wte, WL2t, cbuf, Ain, rel,
                                           bix, bih, bux, buh, box, boh);

  // Internal levels 7..0, 3 fused launches per chunk.
  for (int lvl = 7; lvl >= 0; --lvl) {
    int n = 1 << lvl;
    int base = n - 1;
    int cn = (n < INT_MAXN) ? n : INT_MAXN;
    for (int v0 = 0; v0 < n; v0 += cn) {
      int crows = cn * 128;
      const unsigned short* AinL = Ain + (size_t)(v0 * 128) * 320;
      const unsigned short* AinR = Ain + (size_t)((n + v0) * 128) * 320;
      k_gemm1<<<dim3(8, 2 * cn), 256, 0, stream>>>(AinL, AinR, WA2t, h1, c1,
                                                   FHL, FHR, PR, bsi, bsh, crows);
      k_gemm2<<<dim3(8, cn), 256, 0, stream>>>(h1, WH2t, PR, c1, HT, bsi, bsh);
      k_gemm3<<<dim3(8, cn), 256, 0, stream>>>(HT, wte, WEX2t, FHL, FHR, cbuf, Ain,
                                               rel, out, bix, bih, bux, buh, box, boh,
                                               bfx, bfh, base, v0, n, lvl);
    }
  }
}

// Round 4
// 1075.045 us; speedup vs baseline: 1.0636x; 1.0459x over previous
//
#include <hip/hip_runtime.h>
#include <math.h>

// N=511 complete binary tree: nodes 0..254 internal (both children valid),
// 255..510 leaves. B=128, M=256, IN=512, R=64.
// Gate-interleaved bf16 weight layouts let every LSTM-cell epilogue fuse into
// its producing GEMM. x (word_tag_emb) is converted fp32->bf16 ONCE into a
// node-major buffer so GEMM A-staging is pure vector loads (round-3 rocprof:
// k_leaf was VALU-bound at 36% on per-use pack/convert, MfmaUtil 7.9%).
#define NNODE 511

typedef short s16x8 __attribute__((ext_vector_type(8)));
typedef float f32x4 __attribute__((ext_vector_type(4)));

__device__ __forceinline__ unsigned short f2bf(float f) {
  unsigned int u = __builtin_bit_cast(unsigned int, f);
  u += 0x7fffu + ((u >> 16) & 1u);           // RNE
  return (unsigned short)(u >> 16);
}
__device__ __forceinline__ float sigf(float x) { return 1.0f / (1.0f + expf(-x)); }

// ---------------------------------------------------------------------------
// wte (B,511,512) fp32 -> xbf (node,b,k) bf16, node-major. One-time.
__global__ void k_prep_x(const float* __restrict__ w, unsigned short* __restrict__ xbf) {
  int o = (blockIdx.x * 256 + threadIdx.x) * 4;   // out elem: node*65536 + b*512 + k
  int node = o >> 16;
  int b = (o >> 9) & 127;
  int k = o & 511;
  const float4 v = *(const float4*)(w + ((size_t)b * NNODE + node) * 512 + k);
  unsigned int p0 = (unsigned int)f2bf(v.x) | ((unsigned int)f2bf(v.y) << 16);
  unsigned int p1 = (unsigned int)f2bf(v.z) | ((unsigned int)f2bf(v.w) << 16);
  *(uint2*)(xbf + o) = make_uint2(p0, p1);
}

// ---------------------------------------------------------------------------
// Gate-interleaved transposed weights (c = column index, k = reduction index):
//  WL2t (768,512):  c = 48G+16g+mi, g in {i,u,o};       src W{ix,ux,ox}[k][16G+mi]
//  WA2t (1280,320): c = 80G+16g+mi, g in {i,f,g,o,fh};  g<4: Wsi[k][g*256+m], g=4: k<256?Wfh[k][m]:0
//  WH2t (1024,256): c = 64G+16g+mi, g in {i,f,g,o};     Wsh[k][g*256+m]
//  WEX2t(1024,768): c = 64G+16g+mi, g in {i,u,o,f};     k<256: {Wih,Wuh,Woh,0}[k][m]; else {Wix,Wux,Wox,Wfx}[k-256][m]
__global__ void k_prep_w(const float* __restrict__ Wix, const float* __restrict__ Wux,
                         const float* __restrict__ Wox, const float* __restrict__ Wfx,
                         const float* __restrict__ Wih, const float* __restrict__ Wuh,
                         const float* __restrict__ Woh, const float* __restrict__ Wfh,
                         const float* __restrict__ Wsi, const float* __restrict__ Wsh,
                         unsigned short* __restrict__ WL2t, unsigned short* __restrict__ WA2t,
                         unsigned short* __restrict__ WH2t, unsigned short* __restrict__ WEX2t) {
  int idx = blockIdx.x * 256 + threadIdx.x;
  if (idx < 393216) {                       // WL2t 768*512
    int c = idx >> 9, k = idx & 511;
    int G = c / 48, rem = c - G * 48, g = rem >> 4, mi = rem & 15, m = G * 16 + mi;
    const float* W = (g == 0) ? Wix : (g == 1) ? Wux : Wox;
    WL2t[idx] = f2bf(W[k * 256 + m]);
  } else if (idx < 802816) {                // WA2t 1280*320
    int o = idx - 393216;
    int c = o / 320, k = o - c * 320;
    int G = c / 80, rem = c - G * 80, g = rem >> 4, mi = rem & 15, m = G * 16 + mi;
    float v;
    if (g < 4) v = Wsi[k * 1024 + g * 256 + m];
    else       v = (k < 256) ? Wfh[k * 256 + m] : 0.0f;
    WA2t[o] = f2bf(v);
  } else if (idx < 1064960) {               // WH2t 1024*256
    int o = idx - 802816;
    int c = o >> 8, k = o & 255;
    int G = c >> 6, rem = c & 63, g = rem >> 4, mi = rem & 15, m = G * 16 + mi;
    WH2t[o] = f2bf(Wsh[k * 1024 + g * 256 + m]);
  } else if (idx < 1851392) {               // WEX2t 1024*768
    int o = idx - 1064960;
    int c = o / 768, k = o - c * 768;
    int G = c >> 6, rem = c & 63, g = rem >> 4, mi = rem & 15, m = G * 16 + mi;
    float v;
    if (k < 256) {
      v = (g == 0) ? Wih[k * 256 + m] : (g == 1) ? Wuh[k * 256 + m]
        : (g == 2) ? Woh[k * 256 + m] : 0.0f;
    } else {
      int k2 = k - 256;
      v = (g == 0) ? Wix[k2 * 256 + m] : (g == 1) ? Wux[k2 * 256 + m]
        : (g == 2) ? Wox[k2 * 256 + m] : Wfx[k2 * 256 + m];
    }
    WEX2t[o] = f2bf(v);
  }
}

// Shared MFMA inner step (indices identical to the verified round-2 kernel).
#define MFMA_BODY(NG, CW)                                                     \
  _Pragma("unroll")                                                           \
  for (int kk = 0; kk < 64; kk += 32) {                                       \
    s16x8 af[4], bfr[NG];                                                     \
    _Pragma("unroll")                                                         \
    for (int i = 0; i < 4; ++i)                                               \
      af[i] = *(const s16x8*)(&As[(wm + i * 16 + m16) * 72 + kk + q * 8]);    \
    _Pragma("unroll")                                                         \
    for (int j = 0; j < NG; ++j)                                              \
      bfr[j] = *(const s16x8*)(&Bs[(wc * CW + j * 16 + m16) * 72 + kk + q * 8]); \
    _Pragma("unroll")                                                         \
    for (int i = 0; i < 4; ++i)                                               \
      _Pragma("unroll")                                                       \
      for (int j = 0; j < NG; ++j)                                            \
        acc[i][j] = __builtin_amdgcn_mfma_f32_16x16x32_bf16(af[i], bfr[j], acc[i][j], 0, 0, 0); \
  }

// ---------------------------------------------------------------------------
// GEMM1 + cell1 epilogue. A = [AinL ; AinR] (2*crows x 320 bf16), B = WA2t.
// L rows -> h1 (bf16), c1, FHL.  R rows -> PR (float4 i,f,g,o preacts), FHR.
__global__ __launch_bounds__(256) void k_gemm1(
    const unsigned short* __restrict__ AinL, const unsigned short* __restrict__ AinR,
    const unsigned short* __restrict__ Bt,
    unsigned short* __restrict__ h1, float* __restrict__ c1,
    float* __restrict__ FHL, float* __restrict__ FHR, float* __restrict__ PR,
    const float* __restrict__ bsi, const float* __restrict__ bsh, int crows) {
  __shared__ alignas(16) unsigned short As[128 * 72];
  __shared__ alignas(16) unsigned short Bs[160 * 72];
  const int t = threadIdx.x;
  const int wave = t >> 6, lane = t & 63;
  const int wm = (wave & 1) * 64, wc = wave >> 1;
  const int m16 = lane & 15, q = lane >> 4;
  const int rowBase = blockIdx.y * 128;
  const int colBase = blockIdx.x * 160;
  const bool isL = rowBase < crows;
  const unsigned short* Arow = isL ? (AinL + (size_t)rowBase * 320)
                                   : (AinR + (size_t)(rowBase - crows) * 320);
  f32x4 acc[4][5] = {};

  for (int k0 = 0; k0 < 320; k0 += 64) {
#pragma unroll
    for (int c = 0; c < 4; ++c) {          // A: 1024 chunks of 8
      int chunk = t + 256 * c;
      int row = chunk >> 3, kc = (chunk & 7) << 3;
      *(int4*)(&As[row * 72 + kc]) = *(const int4*)(Arow + (size_t)row * 320 + k0 + kc);
    }
#pragma unroll
    for (int c = 0; c < 5; ++c) {          // B: 1280 chunks of 8
      int chunk = t + 256 * c;
      int row = chunk >> 3, kc = (chunk & 7) << 3;
      *(int4*)(&Bs[row * 72 + kc]) = *(const int4*)(Bt + (size_t)(colBase + row) * 320 + k0 + kc);
    }
    __syncthreads();
    MFMA_BODY(5, 80)
    __syncthreads();
  }

  const int m = (blockIdx.x * 2 + wc) * 16 + m16;
  if (isL) {
    float bi = bsi[m] + bsh[m];
    float bg = bsi[512 + m] + bsh[512 + m];
    float bo = bsi[768 + m] + bsh[768 + m];
#pragma unroll
    for (int i = 0; i < 4; ++i)
#pragma unroll
      for (int r2 = 0; r2 < 4; ++r2) {
        int r = rowBase + wm + i * 16 + q * 4 + r2;
        float ii = sigf(acc[i][0][r2] + bi);
        float gg = tanhf(acc[i][2][r2] + bg);
        float oo = sigf(acc[i][3][r2] + bo);
        float cv = ii * gg;
        size_t o = (size_t)r * 256 + m;
        h1[o] = f2bf(oo * tanhf(cv));
        c1[o] = cv;
        FHL[o] = acc[i][4][r2];
      }
  } else {
#pragma unroll
    for (int i = 0; i < 4; ++i)
#pragma unroll
      for (int r2 = 0; r2 < 4; ++r2) {
        int rr = rowBase - crows + wm + i * 16 + q * 4 + r2;
        size_t o = (size_t)rr * 256 + m;
        float4 pv = {acc[i][0][r2], acc[i][1][r2], acc[i][2][r2], acc[i][3][r2]};
        *(float4*)(PR + o * 4) = pv;
        FHR[o] = acc[i][4][r2];
      }
  }
}

// ---------------------------------------------------------------------------
// GEMM2 + cell2 epilogue. A = h1 (crows x 256), B = WH2t.
// g = acc + PR + b_seq; h_tilde -> HT (bf16).
__global__ __launch_bounds__(256) void k_gemm2(
    const unsigned short* __restrict__ A, const unsigned short* __restrict__ Bt,
    const float* __restrict__ PR, const float* __restrict__ c1,
    unsigned short* __restrict__ HT,
    const float* __restrict__ bsi, const float* __restrict__ bsh) {
  __shared__ alignas(16) unsigned short As[128 * 72];
  __shared__ alignas(16) unsigned short Bs[128 * 72];
  const int t = threadIdx.x;
  const int wave = t >> 6, lane = t & 63;
  const int wm = (wave & 1) * 64, wc = wave >> 1;
  const int m16 = lane & 15, q = lane >> 4;
  const int rowBase = blockIdx.y * 128;
  const int colBase = blockIdx.x * 128;
  f32x4 acc[4][4] = {};

  for (int k0 = 0; k0 < 256; k0 += 64) {
#pragma unroll
    for (int c = 0; c < 4; ++c) {
      int chunk = t + 256 * c;
      int row = chunk >> 3, kc = (chunk & 7) << 3;
      *(int4*)(&As[row * 72 + kc]) = *(const int4*)(A + (size_t)(rowBase + row) * 256 + k0 + kc);
      *(int4*)(&Bs[row * 72 + kc]) = *(const int4*)(Bt + (size_t)(colBase + row) * 256 + k0 + kc);
    }
    __syncthreads();
    MFMA_BODY(4, 64)
    __syncthreads();
  }

  const int m = (blockIdx.x * 2 + wc) * 16 + m16;
  float b0 = bsi[m] + bsh[m];
  float b1 = bsi[256 + m] + bsh[256 + m];
  float b2 = bsi[512 + m] + bsh[512 + m];
  float b3 = bsi[768 + m] + bsh[768 + m];
#pragma unroll
  for (int i = 0; i < 4; ++i)
#pragma unroll
    for (int r2 = 0; r2 < 4; ++r2) {
      int r = rowBase + wm + i * 16 + q * 4 + r2;
      size_t o = (size_t)r * 256 + m;
      float4 pv = *(const float4*)(PR + o * 4);
      float ii = sigf(acc[i][0][r2] + pv.x + b0);
      float ff = sigf(acc[i][1][r2] + pv.y + b1);
      float gg = tanhf(acc[i][2][r2] + pv.z + b2);
      float oo = sigf(acc[i][3][r2] + pv.w + b3);
      float c2 = ff * c1[o] + ii * gg;
      HT[o] = f2bf(oo * tanhf(c2));
    }
}

// ---------------------------------------------------------------------------
// GEMM3 + node-gate epilogue. A = [HT | xbf-slice] (crows x 768 bf16),
// B = WEX2t (gates i,u,o,f). Uses FHL/FHR + children cbuf.
// lvl>0: write cbuf + parent Ain (h bf16, rel). lvl==0: write d_out fp32.
__global__ __launch_bounds__(256) void k_gemm3(
    const unsigned short* __restrict__ HT, const unsigned short* __restrict__ xnode,
    const unsigned short* __restrict__ Bt,
    const float* __restrict__ FHL, const float* __restrict__ FHR,
    float* __restrict__ cbuf, unsigned short* __restrict__ Ain,
    const float* __restrict__ rel, float* __restrict__ out,
    const float* __restrict__ bix, const float* __restrict__ bih,
    const float* __restrict__ bux, const float* __restrict__ buh,
    const float* __restrict__ box, const float* __restrict__ boh,
    const float* __restrict__ bfx, const float* __restrict__ bfh,
    int base, int v0, int n, int lvl) {
  __shared__ alignas(16) unsigned short As[128 * 72];
  __shared__ alignas(16) unsigned short Bs[128 * 72];
  const int t = threadIdx.x;
  const int wave = t >> 6, lane = t & 63;
  const int wm = (wave & 1) * 64, wc = wave >> 1;
  const int m16 = lane & 15, q = lane >> 4;
  const int rowBase = blockIdx.y * 128;
  const int colBase = blockIdx.x * 128;
  f32x4 acc[4][4] = {};

  for (int k0 = 0; k0 < 768; k0 += 64) {
#pragma unroll
    for (int c = 0; c < 4; ++c) {
      int chunk = t + 256 * c;
      int row = chunk >> 3, kc = (chunk & 7) << 3;
      int gr = rowBase + row;
      if (k0 < 256) {
        *(int4*)(&As[row * 72 + kc]) = *(const int4*)(HT + (size_t)gr * 256 + k0 + kc);
      } else {
        *(int4*)(&As[row * 72 + kc]) =
            *(const int4*)(xnode + (size_t)gr * 512 + (k0 - 256) + kc);
      }
      *(int4*)(&Bs[row * 72 + kc]) = *(const int4*)(Bt + (size_t)(colBase + row) * 768 + k0 + kc);
    }
    __syncthreads();
    MFMA_BODY(4, 64)
    __syncthreads();
  }

  const int m = (blockIdx.x * 2 + wc) * 16 + m16;
  float bi = bix[m] + bih[m];
  float bu = bux[m] + buh[m];
  float bo = box[m] + boh[m];
  float bf = bfx[m] + bfh[m];
#pragma unroll
  for (int i = 0; i < 4; ++i)
#pragma unroll
    for (int r2 = 0; r2 < 4; ++r2) {
      int r = rowBase + wm + i * 16 + q * 4 + r2;
      int vloc = r >> 7, b = r & 127;
      int vg = v0 + vloc;
      int node = base + vg;
      int ch0 = 2 * node + 1;
      size_t o = (size_t)r * 256 + m;
      float pf = acc[i][3][r2] + bf;
      float f0 = sigf(pf + FHL[o]);
      float f1 = sigf(pf + FHR[o]);
      float ii = sigf(acc[i][0][r2] + bi);
      float uu = tanhf(acc[i][1][r2] + bu);
      float oo = sigf(acc[i][2][r2] + bo);
      float cc = ii * uu + f0 * cbuf[((size_t)ch0 * 128 + b) * 256 + m]
                         + f1 * cbuf[((size_t)(ch0 + 1) * 128 + b) * 256 + m];
      float hh = oo * tanhf(cc);
      if (lvl == 0) {
        out[b * 256 + m] = hh;
      } else {
        cbuf[((size_t)node * 128 + b) * 256 + m] = cc;
        int rowA = (vg & 1) * (n >> 1) * 128 + (vg >> 1) * 128 + b;
        Ain[(size_t)rowA * 320 + m] = f2bf(hh);
        if (m < 64)
          Ain[(size_t)rowA * 320 + 256 + m] = f2bf(rel[((size_t)b * NNODE + node) * 64 + m]);
      }
    }
}

// ---------------------------------------------------------------------------
// Leaf GEMM + epilogue. A = xbf leaf slice (32768 x 512 bf16), B = WL2t
// (gates i,u,o). c = i*u; writes cbuf + level-7 Ain.
__global__ __launch_bounds__(256) void k_leaf(
    const unsigned short* __restrict__ xleaf, const unsigned short* __restrict__ Bt,
    float* __restrict__ cbuf, unsigned short* __restrict__ Ain,
    const float* __restrict__ rel,
    const float* __restrict__ bix, const float* __restrict__ bih,
    const float* __restrict__ bux, const float* __restrict__ buh,
    const float* __restrict__ box, const float* __restrict__ boh) {
  __shared__ alignas(16) unsigned short As[128 * 72];
  __shared__ alignas(16) unsigned short Bs[96 * 72];
  const int t = threadIdx.x;
  const int wave = t >> 6, lane = t & 63;
  const int wm = (wave & 1) * 64, wc = wave >> 1;
  const int m16 = lane & 15, q = lane >> 4;
  const int rowBase = blockIdx.y * 128;
  const int colBase = blockIdx.x * 96;
  f32x4 acc[4][3] = {};

  for (int k0 = 0; k0 < 512; k0 += 64) {
#pragma unroll
    for (int c = 0; c < 4; ++c) {          // A: bf16 vector loads
      int chunk = t + 256 * c;
      int row = chunk >> 3, kc = (chunk & 7) << 3;
      *(int4*)(&As[row * 72 + kc]) =
          *(const int4*)(xleaf + (size_t)(rowBase + row) * 512 + k0 + kc);
    }
#pragma unroll
    for (int c = 0; c < 3; ++c) {          // B: 768 chunks
      int chunk = t + 256 * c;
      int row = chunk >> 3, kc = (chunk & 7) << 3;
      *(int4*)(&Bs[row * 72 + kc]) = *(const int4*)(Bt + (size_t)(colBase + row) * 512 + k0 + kc);
    }
    __syncthreads();
    MFMA_BODY(3, 48)
    __syncthreads();
  }

  const int m = (blockIdx.x * 2 + wc) * 16 + m16;
  float bi = bix[m] + bih[m];
  float bu = bux[m] + buh[m];
  float bo = box[m] + boh[m];
#pragma unroll
  for (int i = 0; i < 4; ++i)
#pragma unroll
    for (int r2 = 0; r2 < 4; ++r2) {
      int r = rowBase + wm + i * 16 + q * 4 + r2;
      int vg = r >> 7, b = r & 127;
      int node = 255 + vg;
      float ii = sigf(acc[i][0][r2] + bi);
      float uu = tanhf(acc[i][1][r2] + bu);
      float oo = sigf(acc[i][2][r2] + bo);
      float cc = ii * uu;
      float hh = oo * tanhf(cc);
      cbuf[((size_t)node * 128 + b) * 256 + m] = cc;
      int rowA = (vg & 1) * 16384 + (vg >> 1) * 128 + b;
      Ain[(size_t)rowA * 320 + m] = f2bf(hh);
      if (m < 64)
        Ain[(size_t)rowA * 320 + 256 + m] = f2bf(rel[((size_t)b * NNODE + node) * 64 + m]);
    }
}

// ---------------------------------------------------------------------------
extern "C" void kernel_launch(void* const* d_in, const int* in_sizes, int n_in,
                              void* d_out, int out_size, void* d_ws, size_t ws_size,
                              hipStream_t stream) {
  const float* wte = (const float*)d_in[0];
  const float* rel = (const float*)d_in[1];
  const float* Wix = (const float*)d_in[3];
  const float* bix = (const float*)d_in[4];
  const float* Wfx = (const float*)d_in[5];
  const float* bfx = (const float*)d_in[6];
  const float* Wux = (const float*)d_in[7];
  const float* bux = (const float*)d_in[8];
  const float* Wox = (const float*)d_in[9];
  const float* box = (const float*)d_in[10];
  const float* Wih = (const float*)d_in[11];
  const float* bih = (const float*)d_in[12];
  const float* Wfh = (const float*)d_in[13];
  const float* bfh = (const float*)d_in[14];
  const float* Wuh = (const float*)d_in[15];
  const float* buh = (const float*)d_in[16];
  const float* Woh = (const float*)d_in[17];
  const float* boh = (const float*)d_in[18];
  const float* Wsi = (const float*)d_in[19];
  const float* Wsh = (const float*)d_in[20];
  const float* bsi = (const float*)d_in[21];
  const float* bsh = (const float*)d_in[22];
  float* out = (float*)d_out;
  (void)in_sizes; (void)n_in; (void)out_size;

  int INT_MAXN;
  if (ws_size >= (size_t)310 * 1024 * 1024)      INT_MAXN = 128;
  else if (ws_size >= (size_t)200 * 1024 * 1024) INT_MAXN = 32;
  else                                           INT_MAXN = 8;
  const int crowsMax = INT_MAXN * 128;

  char* ws = (char*)d_ws;
  size_t off = 0;
  auto alloc = [&](size_t bytes) {
    size_t o = off; off += (bytes + 255) & ~(size_t)255; return o;
  };
  unsigned short* xbf  = (unsigned short*)(ws + alloc((size_t)NNODE * 128 * 512 * 2));
  float*          cbuf = (float*)         (ws + alloc((size_t)NNODE * 128 * 256 * 4));
  unsigned short* Ain  = (unsigned short*)(ws + alloc((size_t)32768 * 320 * 2));
  unsigned short* WL2t = (unsigned short*)(ws + alloc((size_t)768 * 512 * 2));
  unsigned short* WA2t = (unsigned short*)(ws + alloc((size_t)1280 * 320 * 2));
  unsigned short* WH2t = (unsigned short*)(ws + alloc((size_t)1024 * 256 * 2));
  unsigned short* WEX2t= (unsigned short*)(ws + alloc((size_t)1024 * 768 * 2));
  unsigned short* h1   = (unsigned short*)(ws + alloc((size_t)crowsMax * 256 * 2));
  float*          c1   = (float*)         (ws + alloc((size_t)crowsMax * 256 * 4));
  float*          FHL  = (float*)         (ws + alloc((size_t)crowsMax * 256 * 4));
  float*          FHR  = (float*)         (ws + alloc((size_t)crowsMax * 256 * 4));
  float*          PR   = (float*)         (ws + alloc((size_t)crowsMax * 1024 * 4));
  unsigned short* HT   = (unsigned short*)(ws + alloc((size_t)crowsMax * 256 * 2));

  k_prep_x<<<32704, 256, 0, stream>>>(wte, xbf);
  k_prep_w<<<7232, 256, 0, stream>>>(Wix, Wux, Wox, Wfx, Wih, Wuh, Woh, Wfh,
                                     Wsi, Wsh, WL2t, WA2t, WH2t, WEX2t);

  // Leaves: one fused GEMM over xbf rows [255*128, 511*128).
  k_leaf<<<dim3(8, 256), 256, 0, stream>>>(xbf + (size_t)255 * 128 * 512, WL2t,
                                           cbuf, Ain, rel, bix, bih, bux, buh, box, boh);

  // Internal levels 7..0, 3 fused launches per chunk.
  for (int lvl = 7; lvl >= 0; --lvl) {
    int n = 1 << lvl;
    int base = n - 1;
    int cn = (n < INT_MAXN) ? n : INT_MAXN;
    for (int v0 = 0; v0 < n; v0 += cn) {
      int crows = cn * 128;
      const unsigned short* AinL = Ain + (size_t)(v0 * 128) * 320;
      const unsigned short* AinR = Ain + (size_t)((n + v0) * 128) * 320;
      const unsigned short* xnode = xbf + (size_t)(base + v0) * 128 * 512;
      k_gemm1<<<dim3(8, 2 * cn), 256, 0, stream>>>(AinL, AinR, WA2t, h1, c1,
                                                   FHL, FHR, PR, bsi, bsh, crows);
      k_gemm2<<<dim3(8, cn), 256, 0, stream>>>(h1, WH2t, PR, c1, HT, bsi, bsh);
      k_gemm3<<<dim3(8, cn), 256, 0, stream>>>(HT, xnode, WEX2t, FHL, FHR, cbuf, Ain,
                                               rel, out, bix, bih, bux, buh, box, boh,
                                               bfx, bfh, base, v0, n, lvl);
    }
  }
}

// Round 5
// 1029.887 us; speedup vs baseline: 1.1102x; 1.0438x over previous
//
#include <hip/hip_runtime.h>
#include <math.h>

// N=511 complete binary tree: nodes 0..254 internal (both children valid),
// 255..510 leaves. B=128, M=256, IN=512, R=64.
// Gate-interleaved bf16 weight layouts fuse every LSTM-cell epilogue into its
// producing GEMM. GEMM staging uses global_load_lds width=16 (async direct-to-
// LDS, no VGPR round trip; round-4 rocprof: staging VALU + exposed load latency
// held MfmaUtil at 10%). LDS tiles are unpadded (stride 64 shorts) with an
// XOR k-slot swizzle (slot = kc ^ ((row&7)*8)) compensated in the per-lane
// global source address, so frag ds_read_b128 stays bank-conflict-free.
#define NNODE 511

typedef short s16x8 __attribute__((ext_vector_type(8)));
typedef float f32x4 __attribute__((ext_vector_type(4)));

__device__ __forceinline__ unsigned short f2bf(float f) {
  unsigned int u = __builtin_bit_cast(unsigned int, f);
  u += 0x7fffu + ((u >> 16) & 1u);           // RNE
  return (unsigned short)(u >> 16);
}
__device__ __forceinline__ float sigf(float x) { return 1.0f / (1.0f + expf(-x)); }

__device__ __forceinline__ void load16_lds(const unsigned short* g, unsigned short* l) {
  __builtin_amdgcn_global_load_lds(
      (const __attribute__((address_space(1))) void*)g,
      (__attribute__((address_space(3))) void*)l, 16, 0, 0);
}

// ---------------------------------------------------------------------------
// wte (B,511,512) fp32 -> xbf (node,b,k) bf16, node-major. One-time.
__global__ void k_prep_x(const float* __restrict__ w, unsigned short* __restrict__ xbf) {
  int o = (blockIdx.x * 256 + threadIdx.x) * 4;   // out elem: node*65536 + b*512 + k
  int node = o >> 16;
  int b = (o >> 9) & 127;
  int k = o & 511;
  const float4 v = *(const float4*)(w + ((size_t)b * NNODE + node) * 512 + k);
  unsigned int p0 = (unsigned int)f2bf(v.x) | ((unsigned int)f2bf(v.y) << 16);
  unsigned int p1 = (unsigned int)f2bf(v.z) | ((unsigned int)f2bf(v.w) << 16);
  *(uint2*)(xbf + o) = make_uint2(p0, p1);
}

// ---------------------------------------------------------------------------
// Gate-interleaved transposed weights (c = column index, k = reduction index):
//  WL2t (768,512):  c = 48G+16g+mi, g in {i,u,o}
//  WA2t (1280,320): c = 80G+16g+mi, g in {i,f,g,o,fh}
//  WH2t (1024,256): c = 64G+16g+mi, g in {i,f,g,o}
//  WEX2t(1024,768): c = 64G+16g+mi, g in {i,u,o,f}; k<256 h-weights, k>=256 x-weights
__global__ void k_prep_w(const float* __restrict__ Wix, const float* __restrict__ Wux,
                         const float* __restrict__ Wox, const float* __restrict__ Wfx,
                         const float* __restrict__ Wih, const float* __restrict__ Wuh,
                         const float* __restrict__ Woh, const float* __restrict__ Wfh,
                         const float* __restrict__ Wsi, const float* __restrict__ Wsh,
                         unsigned short* __restrict__ WL2t, unsigned short* __restrict__ WA2t,
                         unsigned short* __restrict__ WH2t, unsigned short* __restrict__ WEX2t) {
  int idx = blockIdx.x * 256 + threadIdx.x;
  if (idx < 393216) {                       // WL2t 768*512
    int c = idx >> 9, k = idx & 511;
    int G = c / 48, rem = c - G * 48, g = rem >> 4, mi = rem & 15, m = G * 16 + mi;
    const float* W = (g == 0) ? Wix : (g == 1) ? Wux : Wox;
    WL2t[idx] = f2bf(W[k * 256 + m]);
  } else if (idx < 802816) {                // WA2t 1280*320
    int o = idx - 393216;
    int c = o / 320, k = o - c * 320;
    int G = c / 80, rem = c - G * 80, g = rem >> 4, mi = rem & 15, m = G * 16 + mi;
    float v;
    if (g < 4) v = Wsi[k * 1024 + g * 256 + m];
    else       v = (k < 256) ? Wfh[k * 256 + m] : 0.0f;
    WA2t[o] = f2bf(v);
  } else if (idx < 1064960) {               // WH2t 1024*256
    int o = idx - 802816;
    int c = o >> 8, k = o & 255;
    int G = c >> 6, rem = c & 63, g = rem >> 4, mi = rem & 15, m = G * 16 + mi;
    WH2t[o] = f2bf(Wsh[k * 1024 + g * 256 + m]);
  } else if (idx < 1851392) {               // WEX2t 1024*768
    int o = idx - 1064960;
    int c = o / 768, k = o - c * 768;
    int G = c >> 6, rem = c & 63, g = rem >> 4, mi = rem & 15, m = G * 16 + mi;
    float v;
    if (k < 256) {
      v = (g == 0) ? Wih[k * 256 + m] : (g == 1) ? Wuh[k * 256 + m]
        : (g == 2) ? Woh[k * 256 + m] : 0.0f;
    } else {
      int k2 = k - 256;
      v = (g == 0) ? Wix[k2 * 256 + m] : (g == 1) ? Wux[k2 * 256 + m]
        : (g == 2) ? Wox[k2 * 256 + m] : Wfx[k2 * 256 + m];
    }
    WEX2t[o] = f2bf(v);
  }
}

// Swizzled MFMA inner step. LDS row stride 64 shorts; k-slot XOR swizzle.
// sw(kk) = (kk | q*8) ^ ((m16&7)*8); row&7 == m16&7 for all our row bases
// (wave row offsets are multiples of 8).
#define MFMA_BODY(NG, CW)                                                     \
  _Pragma("unroll")                                                           \
  for (int kk = 0; kk < 64; kk += 32) {                                       \
    const int sw = (kk | (q * 8)) ^ ((m16 & 7) * 8);                          \
    s16x8 af[4], bfr[NG];                                                     \
    _Pragma("unroll")                                                         \
    for (int i = 0; i < 4; ++i)                                               \
      af[i] = *(const s16x8*)(&As[(wm + i * 16 + m16) * 64 + sw]);            \
    _Pragma("unroll")                                                         \
    for (int j = 0; j < NG; ++j)                                              \
      bfr[j] = *(const s16x8*)(&Bs[(wc * CW + j * 16 + m16) * 64 + sw]);      \
    _Pragma("unroll")                                                         \
    for (int i = 0; i < 4; ++i)                                               \
      _Pragma("unroll")                                                       \
      for (int j = 0; j < NG; ++j)                                            \
        acc[i][j] = __builtin_amdgcn_mfma_f32_16x16x32_bf16(af[i], bfr[j], acc[i][j], 0, 0, 0); \
  }

// Stage R rows x 64 shorts from SRC (row stride STRIDE shorts, starting global
// row 0 of SRC, k offset k0) into DST via global_load_lds. Wave w covers rows
// [w*R/4, (w+1)*R/4), 8 rows per instruction. l8/l7/gsw precomputed.
#define STAGE(DST, SRC, STRIDE, R)                                            \
  _Pragma("unroll")                                                           \
  for (int c = 0; c < (R) / 32; ++c) {                                        \
    int row8 = wave * ((R) / 4) + c * 8;                                      \
    load16_lds(SRC + (size_t)(row8 + l8) * (STRIDE) + k0 + gsw, &DST[row8 * 64]); \
  }

// ---------------------------------------------------------------------------
// GEMM1 + cell1 epilogue. A = [AinL ; AinR] (2*crows x 320 bf16), B = WA2t.
// L rows -> h1 (bf16), c1, FHL.  R rows -> PR (float4 i,f,g,o preacts), FHR.
__global__ __launch_bounds__(256) void k_gemm1(
    const unsigned short* __restrict__ AinL, const unsigned short* __restrict__ AinR,
    const unsigned short* __restrict__ Bt,
    unsigned short* __restrict__ h1, float* __restrict__ c1,
    float* __restrict__ FHL, float* __restrict__ FHR, float* __restrict__ PR,
    const float* __restrict__ bsi, const float* __restrict__ bsh, int crows) {
  __shared__ alignas(16) unsigned short As[128 * 64];
  __shared__ alignas(16) unsigned short Bs[160 * 64];
  const int t = threadIdx.x;
  const int wave = t >> 6, lane = t & 63;
  const int wm = (wave & 1) * 64, wc = wave >> 1;
  const int m16 = lane & 15, q = lane >> 4;
  const int l8 = lane >> 3, l7 = lane & 7;
  const int gsw = ((l7 ^ l8) * 8);
  const int rowBase = blockIdx.y * 128;
  const bool isL = rowBase < crows;
  const unsigned short* Arow = isL ? (AinL + (size_t)rowBase * 320)
                                   : (AinR + (size_t)(rowBase - crows) * 320);
  const unsigned short* Brow = Bt + (size_t)blockIdx.x * 160 * 320;
  f32x4 acc[4][5] = {};

  for (int k0 = 0; k0 < 320; k0 += 64) {
    STAGE(As, Arow, 320, 128)
    STAGE(Bs, Brow, 320, 160)
    __syncthreads();
    MFMA_BODY(5, 80)
    __syncthreads();
  }

  const int m = (blockIdx.x * 2 + wc) * 16 + m16;
  if (isL) {
    float bi = bsi[m] + bsh[m];
    float bg = bsi[512 + m] + bsh[512 + m];
    float bo = bsi[768 + m] + bsh[768 + m];
#pragma unroll
    for (int i = 0; i < 4; ++i)
#pragma unroll
      for (int r2 = 0; r2 < 4; ++r2) {
        int r = rowBase + wm + i * 16 + q * 4 + r2;
        float ii = sigf(acc[i][0][r2] + bi);
        float gg = tanhf(acc[i][2][r2] + bg);
        float oo = sigf(acc[i][3][r2] + bo);
        float cv = ii * gg;
        size_t o = (size_t)r * 256 + m;
        h1[o] = f2bf(oo * tanhf(cv));
        c1[o] = cv;
        FHL[o] = acc[i][4][r2];
      }
  } else {
#pragma unroll
    for (int i = 0; i < 4; ++i)
#pragma unroll
      for (int r2 = 0; r2 < 4; ++r2) {
        int rr = rowBase - crows + wm + i * 16 + q * 4 + r2;
        size_t o = (size_t)rr * 256 + m;
        float4 pv = {acc[i][0][r2], acc[i][1][r2], acc[i][2][r2], acc[i][3][r2]};
        *(float4*)(PR + o * 4) = pv;
        FHR[o] = acc[i][4][r2];
      }
  }
}

// ---------------------------------------------------------------------------
// GEMM2 + cell2 epilogue. A = h1 (crows x 256), B = WH2t.
// g = acc + PR + b_seq; h_tilde -> HT (bf16).
__global__ __launch_bounds__(256) void k_gemm2(
    const unsigned short* __restrict__ A, const unsigned short* __restrict__ Bt,
    const float* __restrict__ PR, const float* __restrict__ c1,
    unsigned short* __restrict__ HT,
    const float* __restrict__ bsi, const float* __restrict__ bsh) {
  __shared__ alignas(16) unsigned short As[128 * 64];
  __shared__ alignas(16) unsigned short Bs[128 * 64];
  const int t = threadIdx.x;
  const int wave = t >> 6, lane = t & 63;
  const int wm = (wave & 1) * 64, wc = wave >> 1;
  const int m16 = lane & 15, q = lane >> 4;
  const int l8 = lane >> 3, l7 = lane & 7;
  const int gsw = ((l7 ^ l8) * 8);
  const int rowBase = blockIdx.y * 128;
  const unsigned short* Arow = A + (size_t)rowBase * 256;
  const unsigned short* Brow = Bt + (size_t)blockIdx.x * 128 * 256;
  f32x4 acc[4][4] = {};

  for (int k0 = 0; k0 < 256; k0 += 64) {
    STAGE(As, Arow, 256, 128)
    STAGE(Bs, Brow, 256, 128)
    __syncthreads();
    MFMA_BODY(4, 64)
    __syncthreads();
  }

  const int m = (blockIdx.x * 2 + wc) * 16 + m16;
  float b0 = bsi[m] + bsh[m];
  float b1 = bsi[256 + m] + bsh[256 + m];
  float b2 = bsi[512 + m] + bsh[512 + m];
  float b3 = bsi[768 + m] + bsh[768 + m];
#pragma unroll
  for (int i = 0; i < 4; ++i)
#pragma unroll
    for (int r2 = 0; r2 < 4; ++r2) {
      int r = rowBase + wm + i * 16 + q * 4 + r2;
      size_t o = (size_t)r * 256 + m;
      float4 pv = *(const float4*)(PR + o * 4);
      float ii = sigf(acc[i][0][r2] + pv.x + b0);
      float ff = sigf(acc[i][1][r2] + pv.y + b1);
      float gg = tanhf(acc[i][2][r2] + pv.z + b2);
      float oo = sigf(acc[i][3][r2] + pv.w + b3);
      float c2 = ff * c1[o] + ii * gg;
      HT[o] = f2bf(oo * tanhf(c2));
    }
}

// ---------------------------------------------------------------------------
// GEMM3 + node-gate epilogue. A = [HT | xbf-slice] (crows x 768 bf16),
// B = WEX2t (gates i,u,o,f). Uses FHL/FHR + children cbuf.
// lvl>0: write cbuf + parent Ain (h bf16, rel). lvl==0: write d_out fp32.
__global__ __launch_bounds__(256) void k_gemm3(
    const unsigned short* __restrict__ HT, const unsigned short* __restrict__ xnode,
    const unsigned short* __restrict__ Bt,
    const float* __restrict__ FHL, const float* __restrict__ FHR,
    float* __restrict__ cbuf, unsigned short* __restrict__ Ain,
    const float* __restrict__ rel, float* __restrict__ out,
    const float* __restrict__ bix, const float* __restrict__ bih,
    const float* __restrict__ bux, const float* __restrict__ buh,
    const float* __restrict__ box, const float* __restrict__ boh,
    const float* __restrict__ bfx, const float* __restrict__ bfh,
    int base, int v0, int n, int lvl) {
  __shared__ alignas(16) unsigned short As[128 * 64];
  __shared__ alignas(16) unsigned short Bs[128 * 64];
  const int t = threadIdx.x;
  const int wave = t >> 6, lane = t & 63;
  const int wm = (wave & 1) * 64, wc = wave >> 1;
  const int m16 = lane & 15, q = lane >> 4;
  const int l8 = lane >> 3, l7 = lane & 7;
  const int gsw = ((l7 ^ l8) * 8);
  const int rowBase = blockIdx.y * 128;
  const unsigned short* Brow = Bt + (size_t)blockIdx.x * 128 * 768;
  f32x4 acc[4][4] = {};

  for (int kb = 0; kb < 768; kb += 64) {
    {
      // A source: k<256 from HT (stride 256), k>=256 from xnode (stride 512).
      const unsigned short* Arow;
      int k0;
      if (kb < 256) { Arow = HT + (size_t)rowBase * 256;    k0 = kb; 
#pragma unroll
        for (int c = 0; c < 4; ++c) {
          int row8 = wave * 32 + c * 8;
          load16_lds(Arow + (size_t)(row8 + l8) * 256 + k0 + gsw, &As[row8 * 64]);
        }
      } else {        Arow = xnode + (size_t)rowBase * 512; k0 = kb - 256;
#pragma unroll
        for (int c = 0; c < 4; ++c) {
          int row8 = wave * 32 + c * 8;
          load16_lds(Arow + (size_t)(row8 + l8) * 512 + k0 + gsw, &As[row8 * 64]);
        }
      }
    }
    {
      int k0 = kb;
      STAGE(Bs, Brow, 768, 128)
    }
    __syncthreads();
    MFMA_BODY(4, 64)
    __syncthreads();
  }

  const int m = (blockIdx.x * 2 + wc) * 16 + m16;
  float bi = bix[m] + bih[m];
  float bu = bux[m] + buh[m];
  float bo = box[m] + boh[m];
  float bf = bfx[m] + bfh[m];
#pragma unroll
  for (int i = 0; i < 4; ++i)
#pragma unroll
    for (int r2 = 0; r2 < 4; ++r2) {
      int r = rowBase + wm + i * 16 + q * 4 + r2;
      int vloc = r >> 7, b = r & 127;
      int vg = v0 + vloc;
      int node = base + vg;
      int ch0 = 2 * node + 1;
      size_t o = (size_t)r * 256 + m;
      float pf = acc[i][3][r2] + bf;
      float f0 = sigf(pf + FHL[o]);
      float f1 = sigf(pf + FHR[o]);
      float ii = sigf(acc[i][0][r2] + bi);
      float uu = tanhf(acc[i][1][r2] + bu);
      float oo = sigf(acc[i][2][r2] + bo);
      float cc = ii * uu + f0 * cbuf[((size_t)ch0 * 128 + b) * 256 + m]
                         + f1 * cbuf[((size_t)(ch0 + 1) * 128 + b) * 256 + m];
      float hh = oo * tanhf(cc);
      if (lvl == 0) {
        out[b * 256 + m] = hh;
      } else {
        cbuf[((size_t)node * 128 + b) * 256 + m] = cc;
        int rowA = (vg & 1) * (n >> 1) * 128 + (vg >> 1) * 128 + b;
        Ain[(size_t)rowA * 320 + m] = f2bf(hh);
        if (m < 64)
          Ain[(size_t)rowA * 320 + 256 + m] = f2bf(rel[((size_t)b * NNODE + node) * 64 + m]);
      }
    }
}

// ---------------------------------------------------------------------------
// Leaf GEMM + epilogue. A = xbf leaf slice (32768 x 512 bf16), B = WL2t
// (gates i,u,o). c = i*u; writes cbuf + level-7 Ain.
__global__ __launch_bounds__(256) void k_leaf(
    const unsigned short* __restrict__ xleaf, const unsigned short* __restrict__ Bt,
    float* __restrict__ cbuf, unsigned short* __restrict__ Ain,
    const float* __restrict__ rel,
    const float* __restrict__ bix, const float* __restrict__ bih,
    const float* __restrict__ bux, const float* __restrict__ buh,
    const float* __restrict__ box, const float* __restrict__ boh) {
  __shared__ alignas(16) unsigned short As[128 * 64];
  __shared__ alignas(16) unsigned short Bs[96 * 64];
  const int t = threadIdx.x;
  const int wave = t >> 6, lane = t & 63;
  const int wm = (wave & 1) * 64, wc = wave >> 1;
  const int m16 = lane & 15, q = lane >> 4;
  const int l8 = lane >> 3, l7 = lane & 7;
  const int gsw = ((l7 ^ l8) * 8);
  const int rowBase = blockIdx.y * 128;
  const unsigned short* Arow = xleaf + (size_t)rowBase * 512;
  const unsigned short* Brow = Bt + (size_t)blockIdx.x * 96 * 512;
  f32x4 acc[4][3] = {};

  for (int k0 = 0; k0 < 512; k0 += 64) {
    STAGE(As, Arow, 512, 128)
    // B: 96 rows -> 24 rows/wave = 3 instrs
#pragma unroll
    for (int c = 0; c < 3; ++c) {
      int row8 = wave * 24 + c * 8;
      load16_lds(Brow + (size_t)(row8 + l8) * 512 + k0 + gsw, &Bs[row8 * 64]);
    }
    __syncthreads();
    MFMA_BODY(3, 48)
    __syncthreads();
  }

  const int m = (blockIdx.x * 2 + wc) * 16 + m16;
  float bi = bix[m] + bih[m];
  float bu = bux[m] + buh[m];
  float bo = box[m] + boh[m];
#pragma unroll
  for (int i = 0; i < 4; ++i)
#pragma unroll
    for (int r2 = 0; r2 < 4; ++r2) {
      int r = rowBase + wm + i * 16 + q * 4 + r2;
      int vg = r >> 7, b = r & 127;
      int node = 255 + vg;
      float ii = sigf(acc[i][0][r2] + bi);
      float uu = tanhf(acc[i][1][r2] + bu);
      float oo = sigf(acc[i][2][r2] + bo);
      float cc = ii * uu;
      float hh = oo * tanhf(cc);
      cbuf[((size_t)node * 128 + b) * 256 + m] = cc;
      int rowA = (vg & 1) * 16384 + (vg >> 1) * 128 + b;
      Ain[(size_t)rowA * 320 + m] = f2bf(hh);
      if (m < 64)
        Ain[(size_t)rowA * 320 + 256 + m] = f2bf(rel[((size_t)b * NNODE + node) * 64 + m]);
    }
}

// ---------------------------------------------------------------------------
extern "C" void kernel_launch(void* const* d_in, const int* in_sizes, int n_in,
                              void* d_out, int out_size, void* d_ws, size_t ws_size,
                              hipStream_t stream) {
  const float* wte = (const float*)d_in[0];
  const float* rel = (const float*)d_in[1];
  const float* Wix = (const float*)d_in[3];
  const float* bix = (const float*)d_in[4];
  const float* Wfx = (const float*)d_in[5];
  const float* bfx = (const float*)d_in[6];
  const float* Wux = (const float*)d_in[7];
  const float* bux = (const float*)d_in[8];
  const float* Wox = (const float*)d_in[9];
  const float* box = (const float*)d_in[10];
  const float* Wih = (const float*)d_in[11];
  const float* bih = (const float*)d_in[12];
  const float* Wfh = (const float*)d_in[13];
  const float* bfh = (const float*)d_in[14];
  const float* Wuh = (const float*)d_in[15];
  const float* buh = (const float*)d_in[16];
  const float* Woh = (const float*)d_in[17];
  const float* boh = (const float*)d_in[18];
  const float* Wsi = (const float*)d_in[19];
  const float* Wsh = (const float*)d_in[20];
  const float* bsi = (const float*)d_in[21];
  const float* bsh = (const float*)d_in[22];
  float* out = (float*)d_out;
  (void)in_sizes; (void)n_in; (void)out_size;

  int INT_MAXN;
  if (ws_size >= (size_t)310 * 1024 * 1024)      INT_MAXN = 128;
  else if (ws_size >= (size_t)200 * 1024 * 1024) INT_MAXN = 32;
  else                                           INT_MAXN = 8;
  const int crowsMax = INT_MAXN * 128;

  char* ws = (char*)d_ws;
  size_t off = 0;
  auto alloc = [&](size_t bytes) {
    size_t o = off; off += (bytes + 255) & ~(size_t)255; return o;
  };
  unsigned short* xbf  = (unsigned short*)(ws + alloc((size_t)NNODE * 128 * 512 * 2));
  float*          cbuf = (float*)         (ws + alloc((size_t)NNODE * 128 * 256 * 4));
  unsigned short* Ain  = (unsigned short*)(ws + alloc((size_t)32768 * 320 * 2));
  unsigned short* WL2t = (unsigned short*)(ws + alloc((size_t)768 * 512 * 2));
  unsigned short* WA2t = (unsigned short*)(ws + alloc((size_t)1280 * 320 * 2));
  unsigned short* WH2t = (unsigned short*)(ws + alloc((size_t)1024 * 256 * 2));
  unsigned short* WEX2t= (unsigned short*)(ws + alloc((size_t)1024 * 768 * 2));
  unsigned short* h1   = (unsigned short*)(ws + alloc((size_t)crowsMax * 256 * 2));
  float*          c1   = (float*)         (ws + alloc((size_t)crowsMax * 256 * 4));
  float*          FHL  = (float*)         (ws + alloc((size_t)crowsMax * 256 * 4));
  float*          FHR  = (float*)         (ws + alloc((size_t)crowsMax * 256 * 4));
  float*          PR   = (float*)         (ws + alloc((size_t)crowsMax * 1024 * 4));
  unsigned short* HT   = (unsigned short*)(ws + alloc((size_t)crowsMax * 256 * 2));

  k_prep_x<<<32704, 256, 0, stream>>>(wte, xbf);
  k_prep_w<<<7232, 256, 0, stream>>>(Wix, Wux, Wox, Wfx, Wih, Wuh, Woh, Wfh,
                                     Wsi, Wsh, WL2t, WA2t, WH2t, WEX2t);

  // Leaves: one fused GEMM over xbf rows [255*128, 511*128).
  k_leaf<<<dim3(8, 256), 256, 0, stream>>>(xbf + (size_t)255 * 128 * 512, WL2t,
                                           cbuf, Ain, rel, bix, bih, bux, buh, box, boh);

  // Internal levels 7..0, 3 fused launches per chunk.
  for (int lvl = 7; lvl >= 0; --lvl) {
    int n = 1 << lvl;
    int base = n - 1;
    int cn = (n < INT_MAXN) ? n : INT_MAXN;
    for (int v0 = 0; v0 < n; v0 += cn) {
      int crows = cn * 128;
      const unsigned short* AinL = Ain + (size_t)(v0 * 128) * 320;
      const unsigned short* AinR = Ain + (size_t)((n + v0) * 128) * 320;
      const unsigned short* xnode = xbf + (size_t)(base + v0) * 128 * 512;
      k_gemm1<<<dim3(8, 2 * cn), 256, 0, stream>>>(AinL, AinR, WA2t, h1, c1,
                                                   FHL, FHR, PR, bsi, bsh, crows);
      k_gemm2<<<dim3(8, cn), 256, 0, stream>>>(h1, WH2t, PR, c1, HT, bsi, bsh);
      k_gemm3<<<dim3(8, cn), 256, 0, stream>>>(HT, xnode, WEX2t, FHL, FHR, cbuf, Ain,
                                               rel, out, bix, bih, bux, buh, box, boh,
                                               bfx, bfh, base, v0, n, lvl);
    }
  }
}